// Round 1
// 109.463 us; speedup vs baseline: 1.0040x; 1.0040x over previous
//
#include <hip/hip_runtime.h>

// Radon transform: data (1,1,512,512) f32, angles (256,) f32 -> out (1,1,256,512) f32.
// Block = (angle, 64-col x-chunk), 512 threads (8 waves). For each 64-row y-chunk,
// stage the rotated patch's bbox (<=92x92) into LDS and bilinear-sample from LDS.
// Staging reads a zero-PADDED image copy (in d_ws) via global_load_lds width=16.
// STRIDE is now a COMPILE-TIME template parameter (95 or 97, chosen per block by
// sign(c) under a block-uniform branch): keeps the per-lane bank step |c +- s| in
// [1, 1.414] (~conflict-free) AND lets the 4 bilinear taps compile to exactly two
// ds_read2_b32 (offsets 0,1 and STRIDE,STRIDE+1) feeding packed v_pk_fma_f32
// vertical lerps. Coordinates advance by DDA ((cx,rx) += (s,c), one v_pk_add_f32).
// Per-sample budget: ~12 VALU + 2 DS (was ~20 VALU + 2-4 DS).

#define HH 512
#define WW 512
#define NA 256
#define XC 64
#define YC 64
#define NXC (WW / XC)          // 8 x-chunks
#define NYC (HH / YC)          // 8 y-chunks
#define NW 8                   // waves per block
#define ROWS_MAX 92
#define STRIDE_MAX 97
#define PAD 112                // >= 256*sqrt(2)-256+2
#define PW (WW + 2 * PAD)      // 736
#define PH (HH + 2 * PAD)      // 736

typedef float f32x2 __attribute__((ext_vector_type(2)));

__global__ __launch_bounds__(256) void pad_kernel(
    const float* __restrict__ img, float* __restrict__ P)
{
    const int c = blockIdx.x * 256 + threadIdx.x;
    const int r = blockIdx.y;
    if (c >= PW) return;
    const int gr = r - PAD, gc = c - PAD;
    float v = 0.0f;
    if ((unsigned)gr < (unsigned)HH && (unsigned)gc < (unsigned)WW)
        v = img[gr * WW + gc];
    P[r * PW + c] = v;
}

__device__ __forceinline__ float fract_f(float x) {
#if __has_builtin(__builtin_amdgcn_fractf)
    return __builtin_amdgcn_fractf(x);
#else
    return x - floorf(x);
#endif
}

template <bool PADDED, int STRIDE>
__device__ __forceinline__ void radon_body(
    const float* __restrict__ src, float* __restrict__ tile,
    const float s, const float c, const int lane, const int wid, const int x0,
    float& acc0, float& acc1)
{
    const float u  = (float)(x0 + lane) + (0.5f - 256.0f);
    const float u0 = (float)x0 + (0.5f - 256.0f);
    const float u1 = u0 + (float)(XC - 1);

    // origin-shifted padded base: valid for row/col indices in [-PAD, WW+PAD)
    const float* __restrict__ Porg = PADDED ? (src + PAD * PW + PAD) : src;

    for (int yc = 0; yc < NYC; ++yc) {
        const float v0 = (float)(yc * YC) + (0.5f - 256.0f);
        const float v1 = v0 + (float)(YC - 1);

        // block-uniform bbox of all bilinear taps for this chunk
        const float cu0 = c * u0, cu1 = c * u1;
        const float sv0 = s * v0, sv1 = s * v1;
        const float su0 = -s * u0, su1 = -s * u1;
        const float cv0 = c * v0, cv1 = c * v1;

        const float cx_min = fminf(cu0, cu1) + fminf(sv0, sv1) + 255.5f;
        const float cx_max = fmaxf(cu0, cu1) + fmaxf(sv0, sv1) + 255.5f;
        const float rx_min = fminf(su0, su1) + fminf(cv0, cv1) + 255.5f;
        const float rx_max = fmaxf(su0, su1) + fmaxf(cv0, cv1) + 255.5f;

        const int c_lo = (int)floorf(cx_min);
        const int c_hi = (int)floorf(cx_max) + 1;
        const int r_lo = (int)floorf(rx_min);
        const int r_hi = (int)floorf(rx_max) + 1;
        int bh = min(r_hi - r_lo + 1, ROWS_MAX);

        // chunk entirely outside image -> contributes exactly 0 (zero padding)
        if (c_lo > WW - 1 || c_hi < 0 || r_lo > HH - 1 || r_hi < 0) continue;

        __syncthreads();   // previous chunk's sampling must finish before overwrite

        if (PADDED) {
            // one global_load_lds_dwordx4 per bbox row: lanes 0..22 each move
            // 16 B -> LDS row base + lane*16 (covers cols 0..91; 368B <= stride*4)
            if (lane < 23) {
                for (int r = wid; r < bh; r += NW) {
                    const float* g = Porg + (r_lo + r) * PW + c_lo + lane * 4;
                    float* l = &tile[r * STRIDE];
                    __builtin_amdgcn_global_load_lds(
                        (__attribute__((address_space(1))) const void*)g,
                        (__attribute__((address_space(3))) void*)l, 16, 0, 0);
                }
            }
        } else {
            const int bw = min(c_hi - c_lo + 1, STRIDE_MAX);
            for (int r = wid; r < bh; r += NW) {
                const int gr = r_lo + r;
                const bool row_ok = ((unsigned)gr < (unsigned)HH);
                const float* __restrict__ rowp = src + gr * WW;
                for (int cc = lane; cc < bw; cc += 64) {
                    const int gc = c_lo + cc;
                    float v = 0.0f;
                    if (row_ok) {
                        const int gcl = min(max(gc, 0), WW - 1);
                        const float t = rowp[gcl];
                        v = ((unsigned)gc < (unsigned)WW) ? t : 0.0f;
                    }
                    tile[r * STRIDE + cc] = v;
                }
            }
        }

        __syncthreads();

        // sample 8 y's per thread from LDS — taps guaranteed inside bbox.
        // DDA: (cx,rx) start at vy0 and advance by (s,c) per y (one v_pk_add_f32).
        const float bc = fmaf(c, u, 255.5f - (float)c_lo);
        const float br = fmaf(-s, u, 255.5f - (float)r_lo);
        const float vy0 = v0 + (float)(wid * 8);

        f32x2 crx;
        crx.x = fmaf(s, vy0, bc);     // local col coord, >= 0
        crx.y = fmaf(c, vy0, br);     // local row coord, >= 0
        f32x2 step;
        step.x = s;
        step.y = c;

#pragma unroll
        for (int i = 0; i < 8; ++i) {
            const float cxl = crx.x;
            const float rxl = crx.y;
            const int ci = (int)cxl;             // == floor for >= 0
            const int ri = (int)rxl;
            const float wx1 = fract_f(cxl);
            const float wy1 = fract_f(rxl);

            __builtin_assume(ri >= 0 && ri < ROWS_MAX);
            __builtin_assume(ci >= 0 && ci < STRIDE_MAX);
            const int ad = ri * STRIDE + ci;

            // two ds_read2_b32: (v00,v01) at offsets (0,1), (v10,v11) at
            // (STRIDE,STRIDE+1) — both immediates encodable (<=255 dwords)
            f32x2 top, bot;
            top.x = tile[ad];
            top.y = tile[ad + 1];
            bot.x = tile[ad + STRIDE];
            bot.y = tile[ad + STRIDE + 1];

            // vertical lerp of both columns, packed: pv = top + wy1*(bot-top)
            f32x2 wyv;
            wyv.x = wy1;
            wyv.y = wy1;
            const f32x2 pv = __builtin_elementwise_fma(wyv, bot - top, top);

            // horizontal lerp, two independent accumulation chains
            acc0 += pv.x;
            acc1 = fmaf(wx1, pv.y - pv.x, acc1);

            crx += step;
        }
    }
}

template <bool PADDED>
__global__ __launch_bounds__(512, 8) void radon_kernel(
    const float* __restrict__ src,   // PADDED ? padded image : raw image
    const float* __restrict__ angles, float* __restrict__ out)
{
    __shared__ float tile[ROWS_MAX * STRIDE_MAX];   // 35.7 KB -> 4 blocks/CU

    const int tid  = threadIdx.x;
    const int lane = tid & 63;
    const int wid  = tid >> 6;     // 0..7

    const int a  = blockIdx.x >> 3;
    const int x0 = (blockIdx.x & 7) * XC;

    float s, c;
    sincosf(angles[a], &s, &c);

    // bank = (ri*stride + ci) % 32; stride 95 (== -1 mod 32) -> bank step c+s,
    // stride 97 (== +1) -> bank step c-s. s>=0: pick so |step| >= 1 always.
    // Block-uniform branch (same c for the whole block) -> __syncthreads safe.
    float acc0 = 0.0f, acc1 = 0.0f;
    if (c >= 0.0f)
        radon_body<PADDED, 95>(src, tile, s, c, lane, wid, x0, acc0, acc1);
    else
        radon_body<PADDED, 97>(src, tile, s, c, lane, wid, x0, acc0, acc1);

    // reduce the 8 y-groups per column and store (each block owns its outputs)
    __syncthreads();
    tile[tid] = acc0 + acc1;
    __syncthreads();
    if (tid < 64) {
        float r = tile[tid];
#pragma unroll
        for (int k = 1; k < NW; ++k) r += tile[k * 64 + tid];
        out[a * WW + x0 + tid] = r;
    }
}

extern "C" void kernel_launch(void* const* d_in, const int* in_sizes, int n_in,
                              void* d_out, int out_size, void* d_ws, size_t ws_size,
                              hipStream_t stream) {
    const float* img    = (const float*)d_in[0];
    const float* angles = (const float*)d_in[1];
    float* out = (float*)d_out;
    float* P   = (float*)d_ws;

    const bool padded = (ws_size >= (size_t)PW * PH * sizeof(float));

    if (padded) {
        pad_kernel<<<dim3((PW + 255) / 256, PH), 256, 0, stream>>>(img, P);
        radon_kernel<true><<<dim3(NA * NXC), 512, 0, stream>>>(P, angles, out);
    } else {
        radon_kernel<false><<<dim3(NA * NXC), 512, 0, stream>>>(img, angles, out);
    }
}